// Round 1
// baseline (670.822 us; speedup 1.0000x reference)
//
#include <hip/hip_runtime.h>

#define G 4
#define S 2048
#define D 1024
#define E 32
#define TOPK 4
#define NTOK (G * S)              // 8192 tokens
#define NROW (NTOK * E)           // 262144 (g,s,e) rows
#define ROWLEN 255                // floats per row (capacity-1)
#define HALF (NROW * ROWLEN)      // 66,846,720 floats per region
#define NFLOAT (2 * HALF + 1)     // 133,693,441 logical output floats (+loss)
#define GEMM_BLOCKS (NTOK / 8)    // 1024 blocks do the gating GEMM
#define ZERO_BLOCKS 8192          // blocks that zero the output

// ---------------------------------------------------------------------------
// Kernel 1 (fused): blocks [0,1024) = gating GEMM + softmax + top-4
//                   blocks [1024, 1024+8192) = zero the whole logical output
// GEMM is read-bound (33.5 MB x), zeroing is write-bound (534.8 MB) -> they
// overlap on HBM; total time ~ max(fill, gemm) instead of sum.
// ---------------------------------------------------------------------------
__global__ __launch_bounds__(256) void prep_kernel(
    const float* __restrict__ x, const float* __restrict__ W,
    const float* __restrict__ b,
    float* __restrict__ gate_ws, int* __restrict__ idx_ws,
    float* __restrict__ out)
{
    const int tid = threadIdx.x;

    if (blockIdx.x >= GEMM_BLOCKS) {
        // ---- output zeroing path: grid-stride float4 stores ----
        const int n4 = NFLOAT >> 2;                  // 33,423,360 float4s
        float4* out4 = (float4*)out;
        int i = (blockIdx.x - GEMM_BLOCKS) * 256 + tid;
        const int stride = ZERO_BLOCKS * 256;
        const float4 z = make_float4(0.f, 0.f, 0.f, 0.f);
        for (; i < n4; i += stride) out4[i] = z;
        if (blockIdx.x == GEMM_BLOCKS && tid == 0)
            out[NFLOAT - 1] = 0.f;                   // loss scalar
        return;
    }

    // ---- gating path: half-wave per token, lane = expert ----
    const int token = blockIdx.x * 8 + (tid >> 5);   // 8 tokens / block
    const int e     = tid & 31;

    const float4* x4 = (const float4*)x;
    const long xb = (long)token * (D / 4);

    float acc = 0.f;
#pragma unroll 4
    for (int d4 = 0; d4 < D / 4; ++d4) {
        float4 xv = x4[xb + d4];
        const float* wp = W + d4 * 4 * E + e;
        acc = fmaf(xv.x, wp[0],     acc);
        acc = fmaf(xv.y, wp[E],     acc);
        acc = fmaf(xv.z, wp[2 * E], acc);
        acc = fmaf(xv.w, wp[3 * E], acc);
    }
    acc += b[e];

    // softmax across the 32 lanes of the half-wave
    float m = acc;
#pragma unroll
    for (int off = 16; off >= 1; off >>= 1)
        m = fmaxf(m, __shfl_xor(m, off, 32));
    float ex = __expf(acc - m);
    float sum = ex;
#pragma unroll
    for (int off = 16; off >= 1; off >>= 1)
        sum += __shfl_xor(sum, off, 32);
    float prob = ex / sum;

    const int g = token >> 11;
    const int s = token & (S - 1);

    // top-4 by repeated argmax; ties -> lowest index (jax.lax.top_k semantics)
    float p = prob;
#pragma unroll
    for (int kk = 0; kk < TOPK; ++kk) {
        float v = p;
        int   vi = e;
#pragma unroll
        for (int off = 16; off >= 1; off >>= 1) {
            float ov = __shfl_xor(v, off, 32);
            int   oi = __shfl_xor(vi, off, 32);
            if (ov > v || (ov == v && oi < vi)) { v = ov; vi = oi; }
        }
        if (e == kk) {
            gate_ws[(kk * G + g) * S + s] = v;
            idx_ws [(kk * G + g) * S + s] = vi;
        }
        if (e == vi) p = -1.f;
    }
}

// ---------------------------------------------------------------------------
// Kernel 2: positions via wave-ballot scan; one wave per (k,g) row.
// Scatters the (at most) 32,768 nonzero {gate, mask} pairs straight into the
// zeroed output. No table, no dense recompute pass.
// ---------------------------------------------------------------------------
__global__ __launch_bounds__(64) void positions_scatter_kernel(
    const int* __restrict__ idx_ws, const float* __restrict__ gate_ws,
    const int* __restrict__ cap_ptr, float* __restrict__ out)
{
    const int row  = blockIdx.x;          // row = k*G + g  (16 rows)
    const int lane = threadIdx.x;         // 0..63
    const int cap  = *cap_ptr;            // 256
    const int g    = row & (G - 1);
    const int* idx = idx_ws + row * S;
    const float* gw = gate_ws + row * S;

    int cnt = 0;                          // running count for expert == lane
    const unsigned long long lowmask = (1ull << lane) - 1ull;

    for (int c = 0; c < S / 64; ++c) {
        const int s  = c * 64 + lane;
        const int my = idx[s];
        unsigned long long eqm = 0ull, mycol = 0ull;
#pragma unroll
        for (int ee = 0; ee < E; ++ee) {
            unsigned long long bal = __ballot(my == ee);
            if (my == ee)   eqm   = bal;
            if (lane == ee) mycol = bal;
        }
        const int prior = __shfl(cnt, my);
        const int pos = prior + __popcll(eqm & lowmask) + 1;
        if (pos < cap) {
            const int off = ((g * S + s) * E + my) * ROWLEN + (pos - 1);
            out[off]        = gw[s];      // combine_tensor
            out[HALF + off] = 1.0f;       // dispatch_mask
        }
        cnt += __popcll(mycol);
    }
}

// ---------------------------------------------------------------------------
extern "C" void kernel_launch(void* const* d_in, const int* in_sizes, int n_in,
                              void* d_out, int out_size, void* d_ws, size_t ws_size,
                              hipStream_t stream)
{
    const float* x   = (const float*)d_in[0];
    const float* W   = (const float*)d_in[1];
    const float* b   = (const float*)d_in[2];
    const int*   cap = (const int*)d_in[3];
    float* out = (float*)d_out;

    const int NA = G * S * TOPK;                       // 32768 assignments
    float* gate_ws = (float*)d_ws;
    int*   idx_ws  = (int*)(gate_ws + NA);

    prep_kernel<<<GEMM_BLOCKS + ZERO_BLOCKS, 256, 0, stream>>>(
        x, W, b, gate_ws, idx_ws, out);
    positions_scatter_kernel<<<G * TOPK, 64, 0, stream>>>(
        idx_ws, gate_ws, cap, out);
}

// Round 2
// 666.757 us; speedup vs baseline: 1.0061x; 1.0061x over previous
//
#include <hip/hip_runtime.h>

#define G 4
#define S 2048
#define D 1024
#define E 32
#define TOPK 4
#define NTOK (G * S)              // 8192 tokens
#define NROW (NTOK * E)           // 262144 (g,s,e) rows
#define ROWLEN 255                // floats per row (capacity-1)
#define HALF (NROW * ROWLEN)      // 66,846,720 floats per region
#define NFLOAT (2 * HALF + 1)     // 133,693,441 logical output floats (+loss)
#define GEMM_BLOCKS (NTOK / 4)    // 2048 blocks, full wave per token
#define ZERO_BLOCKS 8192          // blocks that zero the output

// ---------------------------------------------------------------------------
// Kernel 1 (fused): blocks [0,2048) = gating GEMM + softmax + top-4
//                   blocks [2048, 2048+8192) = zero the whole logical output
// GEMM: one FULL wave per token. Lane l: expert e = l&31, half h = l>>5.
// Each half accumulates D/2, combined with a single shfl_xor(32). This halves
// the GEMM critical path so it hides entirely under the write-bound zeroing.
// ---------------------------------------------------------------------------
__global__ __launch_bounds__(256) void prep_kernel(
    const float* __restrict__ x, const float* __restrict__ W,
    const float* __restrict__ b,
    float* __restrict__ gate_ws, int* __restrict__ idx_ws,
    float* __restrict__ out)
{
    const int tid = threadIdx.x;

    if (blockIdx.x >= GEMM_BLOCKS) {
        // ---- output zeroing path: grid-stride float4 stores ----
        const int n4 = NFLOAT >> 2;                  // 33,423,360 float4s
        float4* out4 = (float4*)out;
        int i = (blockIdx.x - GEMM_BLOCKS) * 256 + tid;
        const int stride = ZERO_BLOCKS * 256;
        const float4 z = make_float4(0.f, 0.f, 0.f, 0.f);
        for (; i < n4; i += stride) out4[i] = z;
        if (blockIdx.x == GEMM_BLOCKS && tid == 0)
            out[NFLOAT - 1] = 0.f;                   // loss scalar
        return;
    }

    // ---- gating path: full wave per token ----
    const int token = blockIdx.x * 4 + (tid >> 6);   // 4 tokens / 256-thr block
    const int e     = tid & 31;                      // expert lane
    const int h     = (tid >> 5) & 1;                // which half of D

    const float4* x4 = (const float4*)x;
    const long xb = (long)token * (D / 4) + (long)h * (D / 8);

    float acc = 0.f;
#pragma unroll 4
    for (int d4 = 0; d4 < D / 8; ++d4) {             // 128 float4s per half
        float4 xv = x4[xb + d4];
        const float* wp = W + (h * (D / 8) + d4) * 4 * E + e;
        acc = fmaf(xv.x, wp[0],     acc);
        acc = fmaf(xv.y, wp[E],     acc);
        acc = fmaf(xv.z, wp[2 * E], acc);
        acc = fmaf(xv.w, wp[3 * E], acc);
    }
    // combine the two halves: pairs (l, l^32) hold the two partial sums
    acc += __shfl_xor(acc, 32);
    acc += b[e];

    // softmax across the 32 lanes of each half (both halves identical now)
    float m = acc;
#pragma unroll
    for (int off = 16; off >= 1; off >>= 1)
        m = fmaxf(m, __shfl_xor(m, off, 32));
    float ex = __expf(acc - m);
    float sum = ex;
#pragma unroll
    for (int off = 16; off >= 1; off >>= 1)
        sum += __shfl_xor(sum, off, 32);
    float prob = ex / sum;

    const int g = token >> 11;
    const int s = token & (S - 1);

    // top-4 by repeated argmax; ties -> lowest index (jax.lax.top_k semantics)
    float p = prob;
#pragma unroll
    for (int kk = 0; kk < TOPK; ++kk) {
        float v = p;
        int   vi = e;
#pragma unroll
        for (int off = 16; off >= 1; off >>= 1) {
            float ov = __shfl_xor(v, off, 32);
            int   oi = __shfl_xor(vi, off, 32);
            if (ov > v || (ov == v && oi < vi)) { v = ov; vi = oi; }
        }
        if (h == 0 && e == kk) {
            gate_ws[(kk * G + g) * S + s] = v;
            idx_ws [(kk * G + g) * S + s] = vi;
        }
        if (e == vi) p = -1.f;
    }
}

// ---------------------------------------------------------------------------
// Kernel 2: positions via wave-ballot scan; one wave per (k,g) row.
// Scatters the (at most) 32,768 nonzero {gate, mask} pairs straight into the
// zeroed output.
// ---------------------------------------------------------------------------
__global__ __launch_bounds__(64) void positions_scatter_kernel(
    const int* __restrict__ idx_ws, const float* __restrict__ gate_ws,
    const int* __restrict__ cap_ptr, float* __restrict__ out)
{
    const int row  = blockIdx.x;          // row = k*G + g  (16 rows)
    const int lane = threadIdx.x;         // 0..63
    const int cap  = *cap_ptr;            // 256
    const int g    = row & (G - 1);
    const int* idx = idx_ws + row * S;
    const float* gw = gate_ws + row * S;

    int cnt = 0;                          // running count for expert == lane
    const unsigned long long lowmask = (1ull << lane) - 1ull;

    for (int c = 0; c < S / 64; ++c) {
        const int s  = c * 64 + lane;
        const int my = idx[s];
        unsigned long long eqm = 0ull, mycol = 0ull;
#pragma unroll
        for (int ee = 0; ee < E; ++ee) {
            unsigned long long bal = __ballot(my == ee);
            if (my == ee)   eqm   = bal;
            if (lane == ee) mycol = bal;
        }
        const int prior = __shfl(cnt, my);
        const int pos = prior + __popcll(eqm & lowmask) + 1;
        if (pos < cap) {
            const int off = ((g * S + s) * E + my) * ROWLEN + (pos - 1);
            out[off]        = gw[s];      // combine_tensor
            out[HALF + off] = 1.0f;       // dispatch_mask
        }
        cnt += __popcll(mycol);
    }
}

// ---------------------------------------------------------------------------
extern "C" void kernel_launch(void* const* d_in, const int* in_sizes, int n_in,
                              void* d_out, int out_size, void* d_ws, size_t ws_size,
                              hipStream_t stream)
{
    const float* x   = (const float*)d_in[0];
    const float* W   = (const float*)d_in[1];
    const float* b   = (const float*)d_in[2];
    const int*   cap = (const int*)d_in[3];
    float* out = (float*)d_out;

    const int NA = G * S * TOPK;                       // 32768 assignments
    float* gate_ws = (float*)d_ws;
    int*   idx_ws  = (int*)(gate_ws + NA);

    prep_kernel<<<GEMM_BLOCKS + ZERO_BLOCKS, 256, 0, stream>>>(
        x, W, b, gate_ws, idx_ws, out);
    positions_scatter_kernel<<<G * TOPK, 64, 0, stream>>>(
        idx_ws, gate_ws, cap, out);
}